// Round 1
// baseline (891.894 us; speedup 1.0000x reference)
//
#include <hip/hip_runtime.h>
#include <hip/hip_bf16.h>

static constexpr int N_NODES  = 100000;
static constexpr int N_EDGES  = 1600000;
static constexpr int DIM_IN   = 768;
static constexpr int DIM_H    = 128;
static constexpr int N_GRAPHS = 64;
static constexpr int NB_SCAN  = (N_NODES + 255) / 256;   // 391

// ---------------------------------------------------------------- degree / dis
__global__ void k_indeg(const int* __restrict__ edst, int* __restrict__ indeg) {
    int e = blockIdx.x * 256 + threadIdx.x;
    if (e < N_EDGES) atomicAdd(&indeg[edst[e]], 1);
}

__global__ void k_dis(const int* __restrict__ indeg, float* __restrict__ dis) {
    int i = blockIdx.x * 256 + threadIdx.x;
    if (i < N_NODES) dis[i] = rsqrtf((float)indeg[i] + 1.0f);  // +1 = self loop
}

// ---------------------------------------------------------------- scan (3 kernels)
__global__ void k_scan1(const int* __restrict__ indeg, int* __restrict__ rp,
                        int* __restrict__ bsum) {
    __shared__ int s[256];
    int t = threadIdx.x;
    int i = blockIdx.x * 256 + t;
    int v = (i < N_NODES) ? indeg[i] : 0;
    s[t] = v;
    __syncthreads();
    for (int off = 1; off < 256; off <<= 1) {
        int x = (t >= off) ? s[t - off] : 0;
        __syncthreads();
        s[t] += x;
        __syncthreads();
    }
    if (i < N_NODES) rp[i] = s[t] - v;           // exclusive (local)
    if (t == 255) bsum[blockIdx.x] = s[255];
}

__global__ void k_scan2(int* __restrict__ bsum) {
    __shared__ int s[512];
    int t = threadIdx.x;
    int v = (t < NB_SCAN) ? bsum[t] : 0;
    s[t] = v;
    __syncthreads();
    for (int off = 1; off < 512; off <<= 1) {
        int x = (t >= off) ? s[t - off] : 0;
        __syncthreads();
        s[t] += x;
        __syncthreads();
    }
    if (t < NB_SCAN) bsum[t] = s[t] - v;         // exclusive block offsets
}

__global__ void k_scan3(int* __restrict__ rp, const int* __restrict__ bsum) {
    int i = blockIdx.x * 256 + threadIdx.x;
    if (i < N_NODES) rp[i] += bsum[blockIdx.x];
}

// ---------------------------------------------------------------- CSR scatter
__global__ void k_scatter(const int* __restrict__ esrc, const int* __restrict__ edst,
                          const int* __restrict__ rp, int* __restrict__ cursor,
                          int* __restrict__ csr) {
    int e = blockIdx.x * 256 + threadIdx.x;
    if (e >= N_EDGES) return;
    int d = edst[e];
    int pos = atomicAdd(&cursor[d], 1);
    csr[rp[d] + pos] = esrc[e];
}

// ---------------------------------------------------------------- GEMM  C[N,128] = A[N,K] @ W[K,128]
#define BM 64
#define BN 128
#define BK 32

__global__ __launch_bounds__(256) void k_gemm(const float* __restrict__ A,
                                              const float* __restrict__ W,
                                              float* __restrict__ C,
                                              int nrows, int K) {
    __shared__ float As[BK][BM + 4];   // +4 pad: rows stay 16B-aligned (68*4=272B)
    __shared__ float Ws[BK][BN];
    int t = threadIdx.x;
    int row0 = blockIdx.x * BM;
    int tr = t >> 4;          // 0..15 -> rows tr*4..+3
    int tc = t & 15;          // 0..15 -> cols tc*8..+7
    int ar = t >> 2;          // 0..63  A-load row
    int ak = (t & 3) * 8;     // 0,8,16,24 A-load k base

    float acc[4][8] = {};

    for (int k0 = 0; k0 < K; k0 += BK) {
        // --- A tile (transposed into LDS) ---
        float4 a0 = make_float4(0, 0, 0, 0), a1 = a0;
        if (row0 + ar < nrows) {
            const float* Aptr = A + (size_t)(row0 + ar) * K + k0 + ak;
            a0 = *(const float4*)(Aptr);
            a1 = *(const float4*)(Aptr + 4);
        }
        As[ak + 0][ar] = a0.x; As[ak + 1][ar] = a0.y;
        As[ak + 2][ar] = a0.z; As[ak + 3][ar] = a0.w;
        As[ak + 4][ar] = a1.x; As[ak + 5][ar] = a1.y;
        As[ak + 6][ar] = a1.z; As[ak + 7][ar] = a1.w;
        // --- W tile ---
        #pragma unroll
        for (int j = 0; j < 16; ++j) {
            int idx = j * 256 + t;          // 0..4095
            int kk = idx >> 7, cc = idx & 127;
            Ws[kk][cc] = W[(size_t)(k0 + kk) * BN + cc];
        }
        __syncthreads();
        #pragma unroll
        for (int kk = 0; kk < BK; ++kk) {
            float4 av = *(const float4*)&As[kk][tr * 4];
            float4 b0 = *(const float4*)&Ws[kk][tc * 8];
            float4 b1 = *(const float4*)&Ws[kk][tc * 8 + 4];
            float a[4] = {av.x, av.y, av.z, av.w};
            float b[8] = {b0.x, b0.y, b0.z, b0.w, b1.x, b1.y, b1.z, b1.w};
            #pragma unroll
            for (int m = 0; m < 4; ++m)
                #pragma unroll
                for (int n = 0; n < 8; ++n)
                    acc[m][n] = fmaf(a[m], b[n], acc[m][n]);
        }
        __syncthreads();
    }
    #pragma unroll
    for (int m = 0; m < 4; ++m) {
        int row = row0 + tr * 4 + m;
        if (row < nrows) {
            float4 o0 = {acc[m][0], acc[m][1], acc[m][2], acc[m][3]};
            float4 o1 = {acc[m][4], acc[m][5], acc[m][6], acc[m][7]};
            *(float4*)&C[(size_t)row * BN + tc * 8]     = o0;
            *(float4*)&C[(size_t)row * BN + tc * 8 + 4] = o1;
        }
    }
}

// ---------------------------------------------------------------- aggregation (1 wave = 1 node)
__global__ __launch_bounds__(256) void k_agg(const float* __restrict__ hin,
                                             const int* __restrict__ csr,
                                             const int* __restrict__ rp,
                                             const int* __restrict__ indeg,
                                             const float* __restrict__ dis,
                                             const float* __restrict__ bias,
                                             float* __restrict__ hout) {
    int node = (blockIdx.x * 256 + threadIdx.x) >> 6;
    int lane = threadIdx.x & 63;
    if (node >= N_NODES) return;
    float di = dis[node];
    int beg = rp[node];
    int cnt = indeg[node];

    // self loop
    float2 v = ((const float2*)(hin + (size_t)node * DIM_H))[lane];
    float ws = di * di;
    float accx = v.x * ws, accy = v.y * ws;

    int e = 0;
    for (; e + 4 <= cnt; e += 4) {
        int s0 = csr[beg + e],     s1 = csr[beg + e + 1];
        int s2 = csr[beg + e + 2], s3 = csr[beg + e + 3];
        float w0 = dis[s0] * di, w1 = dis[s1] * di;
        float w2 = dis[s2] * di, w3 = dis[s3] * di;
        float2 u0 = ((const float2*)(hin + (size_t)s0 * DIM_H))[lane];
        float2 u1 = ((const float2*)(hin + (size_t)s1 * DIM_H))[lane];
        float2 u2 = ((const float2*)(hin + (size_t)s2 * DIM_H))[lane];
        float2 u3 = ((const float2*)(hin + (size_t)s3 * DIM_H))[lane];
        accx += u0.x * w0 + u1.x * w1 + u2.x * w2 + u3.x * w3;
        accy += u0.y * w0 + u1.y * w1 + u2.y * w2 + u3.y * w3;
    }
    for (; e < cnt; ++e) {
        int s = csr[beg + e];
        float w = dis[s] * di;
        float2 u = ((const float2*)(hin + (size_t)s * DIM_H))[lane];
        accx += u.x * w;
        accy += u.y * w;
    }
    float2 b = ((const float2*)bias)[lane];
    float2 o;
    o.x = fmaxf(accx + b.x, 0.f);
    o.y = fmaxf(accy + b.y, 0.f);
    ((float2*)(hout + (size_t)node * DIM_H))[lane] = o;
}

// ---------------------------------------------------------------- mean pool (batch is sorted)
#define POOL_CHUNK 512
__global__ __launch_bounds__(128) void k_pool(const float* __restrict__ h,
                                              const int* __restrict__ batch,
                                              float* __restrict__ pooled,
                                              int* __restrict__ cnt) {
    int c = threadIdx.x;                       // channel 0..127
    int n0 = blockIdx.x * POOL_CHUNK;
    int n1 = min(n0 + POOL_CHUNK, N_NODES);
    if (n0 >= N_NODES) return;
    float acc = 0.f;
    int curg = batch[n0];
    int count = 0;
    for (int n = n0; n < n1; ++n) {
        int g = batch[n];
        if (g != curg) {
            atomicAdd(&pooled[curg * DIM_H + c], acc);
            if (c == 0) atomicAdd(&cnt[curg], count);
            acc = 0.f; count = 0; curg = g;
        }
        acc += h[(size_t)n * DIM_H + c];
        ++count;
    }
    atomicAdd(&pooled[curg * DIM_H + c], acc);
    if (c == 0) atomicAdd(&cnt[curg], count);
}

// ---------------------------------------------------------------- head
__global__ __launch_bounds__(128) void k_head(const float* __restrict__ pooled,
                                              const int* __restrict__ cnt,
                                              const float* __restrict__ Wh,
                                              const float* __restrict__ bh,
                                              float* __restrict__ out) {
    int g = blockIdx.x;
    int c = threadIdx.x;                       // 0..127
    float e = pooled[g * DIM_H + c] / fmaxf((float)cnt[g], 1.0f);
    __shared__ float s0[128], s1[128];
    s0[c] = e * Wh[c * 2 + 0];
    s1[c] = e * Wh[c * 2 + 1];
    __syncthreads();
    for (int off = 64; off > 0; off >>= 1) {
        if (c < off) { s0[c] += s0[c + off]; s1[c] += s1[c + off]; }
        __syncthreads();
    }
    if (c == 0) {
        out[g * 2 + 0] = s0[0] + bh[0];
        out[g * 2 + 1] = s1[0] + bh[1];
    }
}

// ---------------------------------------------------------------- launch
extern "C" void kernel_launch(void* const* d_in, const int* in_sizes, int n_in,
                              void* d_out, int out_size, void* d_ws, size_t ws_size,
                              hipStream_t stream) {
    const float* x    = (const float*)d_in[0];
    const int*   esrc = (const int*)d_in[1];
    const int*   edst = esrc + N_EDGES;
    const int*   batch= (const int*)d_in[2];
    const float* W1   = (const float*)d_in[3];
    const float* b1   = (const float*)d_in[4];
    const float* W2   = (const float*)d_in[5];
    const float* b2   = (const float*)d_in[6];
    const float* Wh   = (const float*)d_in[7];
    const float* bh   = (const float*)d_in[8];
    float* out = (float*)d_out;

    char* ws = (char*)d_ws;
    size_t off = 0;
    auto alloc = [&](size_t bytes) {
        void* p = ws + off;
        off += (bytes + 255) & ~(size_t)255;
        return p;
    };
    float* bufA   = (float*)alloc((size_t)N_NODES * DIM_H * 4);
    float* bufB   = (float*)alloc((size_t)N_NODES * DIM_H * 4);
    float* dis    = (float*)alloc((size_t)N_NODES * 4);
    int*   indeg  = (int*)  alloc((size_t)N_NODES * 4);
    int*   rp     = (int*)  alloc((size_t)N_NODES * 4);
    int*   cursor = (int*)  alloc((size_t)N_NODES * 4);
    int*   csr    = (int*)  alloc((size_t)N_EDGES * 4);
    int*   bsum   = (int*)  alloc(512 * 4);
    float* pooled = (float*)alloc((size_t)N_GRAPHS * DIM_H * 4);
    int*   cnt    = (int*)  alloc((size_t)N_GRAPHS * 4);

    hipMemsetAsync(indeg,  0, (size_t)N_NODES * 4, stream);
    hipMemsetAsync(cursor, 0, (size_t)N_NODES * 4, stream);
    hipMemsetAsync(pooled, 0, (size_t)N_GRAPHS * DIM_H * 4, stream);
    hipMemsetAsync(cnt,    0, (size_t)N_GRAPHS * 4, stream);

    k_indeg  <<<(N_EDGES + 255) / 256, 256, 0, stream>>>(edst, indeg);
    k_dis    <<<(N_NODES + 255) / 256, 256, 0, stream>>>(indeg, dis);
    k_scan1  <<<NB_SCAN, 256, 0, stream>>>(indeg, rp, bsum);
    k_scan2  <<<1, 512, 0, stream>>>(bsum);
    k_scan3  <<<NB_SCAN, 256, 0, stream>>>(rp, bsum);
    k_scatter<<<(N_EDGES + 255) / 256, 256, 0, stream>>>(esrc, edst, rp, cursor, csr);

    k_gemm<<<(N_NODES + BM - 1) / BM, 256, 0, stream>>>(x, W1, bufA, N_NODES, DIM_IN);
    k_agg <<<(N_NODES + 3) / 4, 256, 0, stream>>>(bufA, csr, rp, indeg, dis, b1, bufB);
    k_gemm<<<(N_NODES + BM - 1) / BM, 256, 0, stream>>>(bufB, W2, bufA, N_NODES, DIM_H);
    k_agg <<<(N_NODES + 3) / 4, 256, 0, stream>>>(bufA, csr, rp, indeg, dis, b2, bufB);

    k_pool<<<(N_NODES + POOL_CHUNK - 1) / POOL_CHUNK, 128, 0, stream>>>(bufB, batch, pooled, cnt);
    k_head<<<N_GRAPHS, 128, 0, stream>>>(pooled, cnt, Wh, bh, out);
}

// Round 2
// 601.554 us; speedup vs baseline: 1.4827x; 1.4827x over previous
//
#include <hip/hip_runtime.h>
#include <hip/hip_bf16.h>

static constexpr int N_NODES  = 100000;
static constexpr int N_EDGES  = 1600000;
static constexpr int DIM_IN   = 768;
static constexpr int DIM_H    = 128;
static constexpr int N_GRAPHS = 64;
static constexpr int NB_SCAN  = (N_NODES + 255) / 256;   // 391

typedef __attribute__((ext_vector_type(8))) short short8;
typedef __attribute__((ext_vector_type(4))) float f32x4;

__device__ __forceinline__ ushort f2bf(float f) {   // RNE, finite inputs
    union { float f; uint u; } v; v.f = f;
    uint r = v.u + 0x7fffu + ((v.u >> 16) & 1u);
    return (ushort)(r >> 16);
}
__device__ __forceinline__ float bf2f(ushort u) {
    union { uint u; float f; } v; v.u = ((uint)u) << 16;
    return v.f;
}

// ---------------------------------------------------------------- degree / dis
__global__ void k_indeg(const int* __restrict__ edst, int* __restrict__ indeg) {
    int e = blockIdx.x * 256 + threadIdx.x;
    if (e < N_EDGES) atomicAdd(&indeg[edst[e]], 1);
}

__global__ void k_dis(const int* __restrict__ indeg, float* __restrict__ dis) {
    int i = blockIdx.x * 256 + threadIdx.x;
    if (i < N_NODES) dis[i] = rsqrtf((float)indeg[i] + 1.0f);  // +1 = self loop
}

// ---------------------------------------------------------------- scan
__global__ void k_scan1(const int* __restrict__ indeg, int* __restrict__ rp,
                        int* __restrict__ bsum) {
    __shared__ int s[256];
    int t = threadIdx.x;
    int i = blockIdx.x * 256 + t;
    int v = (i < N_NODES) ? indeg[i] : 0;
    s[t] = v;
    __syncthreads();
    for (int off = 1; off < 256; off <<= 1) {
        int x = (t >= off) ? s[t - off] : 0;
        __syncthreads();
        s[t] += x;
        __syncthreads();
    }
    if (i < N_NODES) rp[i] = s[t] - v;
    if (t == 255) bsum[blockIdx.x] = s[255];
}

__global__ void k_scan2(int* __restrict__ bsum) {
    __shared__ int s[512];
    int t = threadIdx.x;
    int v = (t < NB_SCAN) ? bsum[t] : 0;
    s[t] = v;
    __syncthreads();
    for (int off = 1; off < 512; off <<= 1) {
        int x = (t >= off) ? s[t - off] : 0;
        __syncthreads();
        s[t] += x;
        __syncthreads();
    }
    if (t < NB_SCAN) bsum[t] = s[t] - v;
}

__global__ void k_scan3(int* __restrict__ rp, const int* __restrict__ bsum) {
    int i = blockIdx.x * 256 + threadIdx.x;
    if (i < N_NODES) rp[i] += bsum[blockIdx.x];
}

// ---------------------------------------------------------------- CSR scatter
__global__ void k_scatter(const int* __restrict__ esrc, const int* __restrict__ edst,
                          const int* __restrict__ rp, int* __restrict__ cursor,
                          int* __restrict__ csr) {
    int e = blockIdx.x * 256 + threadIdx.x;
    if (e >= N_EDGES) return;
    int d = edst[e];
    int pos = atomicAdd(&cursor[d], 1);
    csr[rp[d] + pos] = esrc[e];
}

// ---------------------------------------------------------------- W convert: [K][128] fp32 -> transposed bf16 hi/lo [128][K]
__global__ void k_convW(const float* __restrict__ W, ushort* __restrict__ Wth,
                        ushort* __restrict__ Wtl, int K) {
    int i = blockIdx.x * 256 + threadIdx.x;
    if (i >= K * 128) return;
    int k = i >> 7, n = i & 127;
    float w = W[i];
    ushort h = f2bf(w);
    ushort lo = f2bf(w - bf2f(h));
    Wth[(size_t)n * K + k] = h;
    Wtl[(size_t)n * K + k] = lo;
}

// ---------------------------------------------------------------- MFMA GEMM
// C[nrows][128](bf16) = A[nrows][K] @ (W_hi + W_lo)   (W stored transposed [128][K])
// 128x128 tile, 4 waves (2x2 of 64x64), 16x16x32 bf16 MFMA.
#define LDSTR 40   // padded LDS row stride in bf16 elems (80B: <=2-way bank alias, free)

template<int K, bool AFP32>
__global__ __launch_bounds__(256) void k_gemm_mfma(const void* __restrict__ Av,
                                                   const ushort* __restrict__ Wth,
                                                   const ushort* __restrict__ Wtl,
                                                   ushort* __restrict__ C,
                                                   int nrows) {
    __shared__ ushort As[128 * LDSTR];
    __shared__ ushort Bh[128 * LDSTR];
    __shared__ ushort Bl[128 * LDSTR];

    const int t = threadIdx.x;
    const int row0 = blockIdx.x * 128;
    const int srow = t >> 1;             // staging row 0..127
    const int skoff = (t & 1) * 16;      // staging k-offset 0/16
    const int l = t & 63;
    const int wv = t >> 6;
    const int wm = wv >> 1, wn = wv & 1; // wave 2x2
    const int lr = l & 15;
    const int lk = (l >> 4) * 8;

    f32x4 acc[4][4];
    const f32x4 zero = {0.f, 0.f, 0.f, 0.f};
    #pragma unroll
    for (int m = 0; m < 4; ++m)
        #pragma unroll
        for (int n = 0; n < 4; ++n) acc[m][n] = zero;

    for (int k0 = 0; k0 < K; k0 += 32) {
        // ---- stage A tile [128][32] as bf16 ----
        {
            uint p[8];
            if (AFP32) {
                float f[16];
                if (row0 + srow < nrows) {
                    const float4* Ap = (const float4*)((const float*)Av +
                        (size_t)(row0 + srow) * K + k0 + skoff);
                    *(float4*)&f[0]  = Ap[0];
                    *(float4*)&f[4]  = Ap[1];
                    *(float4*)&f[8]  = Ap[2];
                    *(float4*)&f[12] = Ap[3];
                } else {
                    #pragma unroll
                    for (int i = 0; i < 16; ++i) f[i] = 0.f;
                }
                #pragma unroll
                for (int i = 0; i < 8; ++i)
                    p[i] = (uint)f2bf(f[2 * i]) | ((uint)f2bf(f[2 * i + 1]) << 16);
            } else {
                uint4 q0 = {0, 0, 0, 0}, q1 = {0, 0, 0, 0};
                if (row0 + srow < nrows) {
                    const uint4* Ap = (const uint4*)((const ushort*)Av +
                        (size_t)(row0 + srow) * K + k0 + skoff);
                    q0 = Ap[0]; q1 = Ap[1];
                }
                p[0] = q0.x; p[1] = q0.y; p[2] = q0.z; p[3] = q0.w;
                p[4] = q1.x; p[5] = q1.y; p[6] = q1.z; p[7] = q1.w;
            }
            uint4 w0 = {p[0], p[1], p[2], p[3]};
            uint4 w1 = {p[4], p[5], p[6], p[7]};
            *(uint4*)&As[srow * LDSTR + skoff]     = w0;
            *(uint4*)&As[srow * LDSTR + skoff + 8] = w1;
        }
        // ---- stage W hi/lo tiles [128 n][32 k] ----
        {
            const uint4* Wp = (const uint4*)(Wth + (size_t)srow * K + k0 + skoff);
            *(uint4*)&Bh[srow * LDSTR + skoff]     = Wp[0];
            *(uint4*)&Bh[srow * LDSTR + skoff + 8] = Wp[1];
            const uint4* Wq = (const uint4*)(Wtl + (size_t)srow * K + k0 + skoff);
            *(uint4*)&Bl[srow * LDSTR + skoff]     = Wq[0];
            *(uint4*)&Bl[srow * LDSTR + skoff + 8] = Wq[1];
        }
        __syncthreads();

        short8 a[4], bh[4], bl[4];
        #pragma unroll
        for (int m = 0; m < 4; ++m)
            a[m] = *(const short8*)&As[(wm * 64 + m * 16 + lr) * LDSTR + lk];
        #pragma unroll
        for (int n = 0; n < 4; ++n) {
            bh[n] = *(const short8*)&Bh[(wn * 64 + n * 16 + lr) * LDSTR + lk];
            bl[n] = *(const short8*)&Bl[(wn * 64 + n * 16 + lr) * LDSTR + lk];
        }
        #pragma unroll
        for (int m = 0; m < 4; ++m)
            #pragma unroll
            for (int n = 0; n < 4; ++n) {
                acc[m][n] = __builtin_amdgcn_mfma_f32_16x16x32_bf16(a[m], bh[n], acc[m][n], 0, 0, 0);
                acc[m][n] = __builtin_amdgcn_mfma_f32_16x16x32_bf16(a[m], bl[n], acc[m][n], 0, 0, 0);
            }
        __syncthreads();
    }

    // ---- epilogue: C/D layout col=lane&15, row=(lane>>4)*4+j ----
    #pragma unroll
    for (int m = 0; m < 4; ++m) {
        #pragma unroll
        for (int n = 0; n < 4; ++n) {
            int col = wn * 64 + n * 16 + lr;
            #pragma unroll
            for (int j = 0; j < 4; ++j) {
                int row = row0 + wm * 64 + m * 16 + (l >> 4) * 4 + j;
                if (row < nrows)
                    C[(size_t)row * DIM_H + col] = f2bf(acc[m][n][j]);
            }
        }
    }
}

// ---------------------------------------------------------------- aggregation (bf16 in/out, 1 wave = 1 node)
__global__ __launch_bounds__(256) void k_agg(const ushort* __restrict__ hin,
                                             const int* __restrict__ csr,
                                             const int* __restrict__ rp,
                                             const int* __restrict__ indeg,
                                             const float* __restrict__ dis,
                                             const float* __restrict__ bias,
                                             ushort* __restrict__ hout) {
    int node = (blockIdx.x * 256 + threadIdx.x) >> 6;
    int lane = threadIdx.x & 63;
    if (node >= N_NODES) return;
    float di = dis[node];
    int beg = rp[node];
    int cnt = indeg[node];

    // self loop
    uint v = ((const uint*)(hin + (size_t)node * DIM_H))[lane];
    float ws = di * di;
    float accx = bf2f((ushort)(v & 0xffff)) * ws;
    float accy = bf2f((ushort)(v >> 16)) * ws;

    int e = 0;
    for (; e + 4 <= cnt; e += 4) {
        int s0 = csr[beg + e],     s1 = csr[beg + e + 1];
        int s2 = csr[beg + e + 2], s3 = csr[beg + e + 3];
        float w0 = dis[s0] * di, w1 = dis[s1] * di;
        float w2 = dis[s2] * di, w3 = dis[s3] * di;
        uint u0 = ((const uint*)(hin + (size_t)s0 * DIM_H))[lane];
        uint u1 = ((const uint*)(hin + (size_t)s1 * DIM_H))[lane];
        uint u2 = ((const uint*)(hin + (size_t)s2 * DIM_H))[lane];
        uint u3 = ((const uint*)(hin + (size_t)s3 * DIM_H))[lane];
        accx += bf2f((ushort)(u0 & 0xffff)) * w0 + bf2f((ushort)(u1 & 0xffff)) * w1
              + bf2f((ushort)(u2 & 0xffff)) * w2 + bf2f((ushort)(u3 & 0xffff)) * w3;
        accy += bf2f((ushort)(u0 >> 16)) * w0 + bf2f((ushort)(u1 >> 16)) * w1
              + bf2f((ushort)(u2 >> 16)) * w2 + bf2f((ushort)(u3 >> 16)) * w3;
    }
    for (; e < cnt; ++e) {
        int s = csr[beg + e];
        float w = dis[s] * di;
        uint u = ((const uint*)(hin + (size_t)s * DIM_H))[lane];
        accx += bf2f((ushort)(u & 0xffff)) * w;
        accy += bf2f((ushort)(u >> 16)) * w;
    }
    float2 b = ((const float2*)bias)[lane];
    float ox = fmaxf(accx + b.x, 0.f);
    float oy = fmaxf(accy + b.y, 0.f);
    uint packed = (uint)f2bf(ox) | ((uint)f2bf(oy) << 16);
    ((uint*)(hout + (size_t)node * DIM_H))[lane] = packed;
}

// ---------------------------------------------------------------- mean pool (batch sorted, bf16 in)
#define POOL_CHUNK 512
__global__ __launch_bounds__(128) void k_pool(const ushort* __restrict__ h,
                                              const int* __restrict__ batch,
                                              float* __restrict__ pooled,
                                              int* __restrict__ cnt) {
    int c = threadIdx.x;
    int n0 = blockIdx.x * POOL_CHUNK;
    int n1 = min(n0 + POOL_CHUNK, N_NODES);
    if (n0 >= N_NODES) return;
    float acc = 0.f;
    int curg = batch[n0];
    int count = 0;
    for (int n = n0; n < n1; ++n) {
        int g = batch[n];
        if (g != curg) {
            atomicAdd(&pooled[curg * DIM_H + c], acc);
            if (c == 0) atomicAdd(&cnt[curg], count);
            acc = 0.f; count = 0; curg = g;
        }
        acc += bf2f(h[(size_t)n * DIM_H + c]);
        ++count;
    }
    atomicAdd(&pooled[curg * DIM_H + c], acc);
    if (c == 0) atomicAdd(&cnt[curg], count);
}

// ---------------------------------------------------------------- head
__global__ __launch_bounds__(128) void k_head(const float* __restrict__ pooled,
                                              const int* __restrict__ cnt,
                                              const float* __restrict__ Wh,
                                              const float* __restrict__ bh,
                                              float* __restrict__ out) {
    int g = blockIdx.x;
    int c = threadIdx.x;
    float e = pooled[g * DIM_H + c] / fmaxf((float)cnt[g], 1.0f);
    __shared__ float s0[128], s1[128];
    s0[c] = e * Wh[c * 2 + 0];
    s1[c] = e * Wh[c * 2 + 1];
    __syncthreads();
    for (int off = 64; off > 0; off >>= 1) {
        if (c < off) { s0[c] += s0[c + off]; s1[c] += s1[c + off]; }
        __syncthreads();
    }
    if (c == 0) {
        out[g * 2 + 0] = s0[0] + bh[0];
        out[g * 2 + 1] = s1[0] + bh[1];
    }
}

// ---------------------------------------------------------------- launch
extern "C" void kernel_launch(void* const* d_in, const int* in_sizes, int n_in,
                              void* d_out, int out_size, void* d_ws, size_t ws_size,
                              hipStream_t stream) {
    const float* x    = (const float*)d_in[0];
    const int*   esrc = (const int*)d_in[1];
    const int*   edst = esrc + N_EDGES;
    const int*   batch= (const int*)d_in[2];
    const float* W1   = (const float*)d_in[3];
    const float* b1   = (const float*)d_in[4];
    const float* W2   = (const float*)d_in[5];
    const float* b2   = (const float*)d_in[6];
    const float* Wh   = (const float*)d_in[7];
    const float* bh   = (const float*)d_in[8];
    float* out = (float*)d_out;

    char* ws = (char*)d_ws;
    size_t off = 0;
    auto alloc = [&](size_t bytes) {
        void* p = ws + off;
        off += (bytes + 255) & ~(size_t)255;
        return p;
    };
    ushort* bufZ  = (ushort*)alloc((size_t)N_NODES * DIM_H * 2);
    ushort* bufH  = (ushort*)alloc((size_t)N_NODES * DIM_H * 2);
    float*  dis   = (float*)alloc((size_t)N_NODES * 4);
    int*    indeg = (int*)  alloc((size_t)N_NODES * 4);
    int*    rp    = (int*)  alloc((size_t)N_NODES * 4);
    int*    cursor= (int*)  alloc((size_t)N_NODES * 4);
    int*    csr   = (int*)  alloc((size_t)N_EDGES * 4);
    int*    bsum  = (int*)  alloc(512 * 4);
    float*  pooled= (float*)alloc((size_t)N_GRAPHS * DIM_H * 4);
    int*    cnt   = (int*)  alloc((size_t)N_GRAPHS * 4);
    ushort* W1th  = (ushort*)alloc((size_t)DIM_IN * DIM_H * 2);
    ushort* W1tl  = (ushort*)alloc((size_t)DIM_IN * DIM_H * 2);
    ushort* W2th  = (ushort*)alloc((size_t)DIM_H * DIM_H * 2);
    ushort* W2tl  = (ushort*)alloc((size_t)DIM_H * DIM_H * 2);

    hipMemsetAsync(indeg,  0, (size_t)N_NODES * 4, stream);
    hipMemsetAsync(cursor, 0, (size_t)N_NODES * 4, stream);
    hipMemsetAsync(pooled, 0, (size_t)N_GRAPHS * DIM_H * 4, stream);
    hipMemsetAsync(cnt,    0, (size_t)N_GRAPHS * 4, stream);

    k_convW  <<<(DIM_IN * DIM_H + 255) / 256, 256, 0, stream>>>(W1, W1th, W1tl, DIM_IN);
    k_convW  <<<(DIM_H * DIM_H + 255) / 256, 256, 0, stream>>>(W2, W2th, W2tl, DIM_H);

    k_indeg  <<<(N_EDGES + 255) / 256, 256, 0, stream>>>(edst, indeg);
    k_dis    <<<(N_NODES + 255) / 256, 256, 0, stream>>>(indeg, dis);
    k_scan1  <<<NB_SCAN, 256, 0, stream>>>(indeg, rp, bsum);
    k_scan2  <<<1, 512, 0, stream>>>(bsum);
    k_scan3  <<<NB_SCAN, 256, 0, stream>>>(rp, bsum);
    k_scatter<<<(N_EDGES + 255) / 256, 256, 0, stream>>>(esrc, edst, rp, cursor, csr);

    int gblocks = (N_NODES + 127) / 128;
    k_gemm_mfma<DIM_IN, true ><<<gblocks, 256, 0, stream>>>(x,    W1th, W1tl, bufZ, N_NODES);
    k_agg<<<(N_NODES + 3) / 4, 256, 0, stream>>>(bufZ, csr, rp, indeg, dis, b1, bufH);
    k_gemm_mfma<DIM_H,  false><<<gblocks, 256, 0, stream>>>(bufH, W2th, W2tl, bufZ, N_NODES);
    k_agg<<<(N_NODES + 3) / 4, 256, 0, stream>>>(bufZ, csr, rp, indeg, dis, b2, bufH);

    k_pool<<<(N_NODES + POOL_CHUNK - 1) / POOL_CHUNK, 128, 0, stream>>>(bufH, batch, pooled, cnt);
    k_head<<<N_GRAPHS, 128, 0, stream>>>(pooled, cnt, Wh, bh, out);
}

// Round 3
// 488.077 us; speedup vs baseline: 1.8274x; 1.2325x over previous
//
#include <hip/hip_runtime.h>
#include <hip/hip_bf16.h>

static constexpr int N_NODES  = 100000;
static constexpr int N_EDGES  = 1600000;
static constexpr int DIM_IN   = 768;
static constexpr int DIM_H    = 128;
static constexpr int N_GRAPHS = 64;
static constexpr int NB_SCAN  = (N_NODES + 255) / 256;   // 391

typedef __attribute__((ext_vector_type(8))) short short8;
typedef __attribute__((ext_vector_type(4))) float f32x4;

__device__ __forceinline__ ushort f2bf(float f) {   // RNE, finite inputs
    union { float f; uint u; } v; v.f = f;
    uint r = v.u + 0x7fffu + ((v.u >> 16) & 1u);
    return (ushort)(r >> 16);
}
__device__ __forceinline__ float bf2f(ushort u) {
    union { uint u; float f; } v; v.u = ((uint)u) << 16;
    return v.f;
}

// ---------------------------------------------------------------- degree
__global__ void k_indeg(const int* __restrict__ edst, int* __restrict__ indeg) {
    int e = blockIdx.x * 256 + threadIdx.x;
    if (e < N_EDGES) atomicAdd(&indeg[edst[e]], 1);
}

// ---------------------------------------------------------------- scan (+dis fold)
__global__ void k_scan1(const int* __restrict__ indeg, int* __restrict__ rp,
                        int* __restrict__ bsum, float* __restrict__ dis) {
    __shared__ int s[256];
    int t = threadIdx.x;
    int i = blockIdx.x * 256 + t;
    int v = (i < N_NODES) ? indeg[i] : 0;
    s[t] = v;
    __syncthreads();
    for (int off = 1; off < 256; off <<= 1) {
        int x = (t >= off) ? s[t - off] : 0;
        __syncthreads();
        s[t] += x;
        __syncthreads();
    }
    if (i < N_NODES) {
        rp[i] = s[t] - v;                       // exclusive (block-local)
        dis[i] = rsqrtf((float)v + 1.0f);       // +1 = self loop
    }
    if (t == 255) bsum[blockIdx.x] = s[255];
}

__global__ void k_scan2(int* __restrict__ bsum) {
    __shared__ int s[512];
    int t = threadIdx.x;
    int v = (t < NB_SCAN) ? bsum[t] : 0;
    s[t] = v;
    __syncthreads();
    for (int off = 1; off < 512; off <<= 1) {
        int x = (t >= off) ? s[t - off] : 0;
        __syncthreads();
        s[t] += x;
        __syncthreads();
    }
    if (t < NB_SCAN) bsum[t] = s[t] - v;        // exclusive block offsets
}

// ---------------------------------------------------------------- CSR scatter (scan3 folded)
__global__ void k_scatter(const int* __restrict__ esrc, const int* __restrict__ edst,
                          const int* __restrict__ rp, const int* __restrict__ bsum,
                          int* __restrict__ cursor, int* __restrict__ csr) {
    int e = blockIdx.x * 256 + threadIdx.x;
    if (e >= N_EDGES) return;
    int d = edst[e];
    int pos = atomicAdd(&cursor[d], 1);
    csr[rp[d] + bsum[d >> 8] + pos] = esrc[e];
}

// ---------------------------------------------------------------- graph row pointers (batch sorted)
__global__ void k_gstart(const int* __restrict__ batch, int* __restrict__ gstart) {
    int g = threadIdx.x;
    if (g > N_GRAPHS) return;
    int lo = 0, hi = N_NODES;
    while (lo < hi) {                            // lower_bound(batch, g)
        int mid = (lo + hi) >> 1;
        if (batch[mid] < g) lo = mid + 1; else hi = mid;
    }
    gstart[g] = lo;
}

// ---------------------------------------------------------------- W convert: [K][128] fp32 -> transposed bf16 hi/lo [128][K]
__global__ void k_convW(const float* __restrict__ W, ushort* __restrict__ Wth,
                        ushort* __restrict__ Wtl, int K) {
    int i = blockIdx.x * 256 + threadIdx.x;
    if (i >= K * 128) return;
    int k = i >> 7, n = i & 127;
    float w = W[i];
    ushort h = f2bf(w);
    ushort lo = f2bf(w - bf2f(h));
    Wth[(size_t)n * K + k] = h;
    Wtl[(size_t)n * K + k] = lo;
}

// ---------------------------------------------------------------- MFMA GEMM
// C[nrows][128](bf16) = A[nrows][K] @ (W_hi + W_lo)   (W stored transposed [128][K])
#define LDSTR 40

template<int K, bool AFP32>
__global__ __launch_bounds__(256) void k_gemm_mfma(const void* __restrict__ Av,
                                                   const ushort* __restrict__ Wth,
                                                   const ushort* __restrict__ Wtl,
                                                   ushort* __restrict__ C,
                                                   int nrows) {
    __shared__ ushort As[128 * LDSTR];
    __shared__ ushort Bh[128 * LDSTR];
    __shared__ ushort Bl[128 * LDSTR];

    const int t = threadIdx.x;
    const int row0 = blockIdx.x * 128;
    const int srow = t >> 1;
    const int skoff = (t & 1) * 16;
    const int l = t & 63;
    const int wv = t >> 6;
    const int wm = wv >> 1, wn = wv & 1;
    const int lr = l & 15;
    const int lk = (l >> 4) * 8;

    f32x4 acc[4][4];
    const f32x4 zero = {0.f, 0.f, 0.f, 0.f};
    #pragma unroll
    for (int m = 0; m < 4; ++m)
        #pragma unroll
        for (int n = 0; n < 4; ++n) acc[m][n] = zero;

    for (int k0 = 0; k0 < K; k0 += 32) {
        {
            uint p[8];
            if (AFP32) {
                float f[16];
                if (row0 + srow < nrows) {
                    const float4* Ap = (const float4*)((const float*)Av +
                        (size_t)(row0 + srow) * K + k0 + skoff);
                    *(float4*)&f[0]  = Ap[0];
                    *(float4*)&f[4]  = Ap[1];
                    *(float4*)&f[8]  = Ap[2];
                    *(float4*)&f[12] = Ap[3];
                } else {
                    #pragma unroll
                    for (int i = 0; i < 16; ++i) f[i] = 0.f;
                }
                #pragma unroll
                for (int i = 0; i < 8; ++i)
                    p[i] = (uint)f2bf(f[2 * i]) | ((uint)f2bf(f[2 * i + 1]) << 16);
            } else {
                uint4 q0 = {0, 0, 0, 0}, q1 = {0, 0, 0, 0};
                if (row0 + srow < nrows) {
                    const uint4* Ap = (const uint4*)((const ushort*)Av +
                        (size_t)(row0 + srow) * K + k0 + skoff);
                    q0 = Ap[0]; q1 = Ap[1];
                }
                p[0] = q0.x; p[1] = q0.y; p[2] = q0.z; p[3] = q0.w;
                p[4] = q1.x; p[5] = q1.y; p[6] = q1.z; p[7] = q1.w;
            }
            uint4 w0 = {p[0], p[1], p[2], p[3]};
            uint4 w1 = {p[4], p[5], p[6], p[7]};
            *(uint4*)&As[srow * LDSTR + skoff]     = w0;
            *(uint4*)&As[srow * LDSTR + skoff + 8] = w1;
        }
        {
            const uint4* Wp = (const uint4*)(Wth + (size_t)srow * K + k0 + skoff);
            *(uint4*)&Bh[srow * LDSTR + skoff]     = Wp[0];
            *(uint4*)&Bh[srow * LDSTR + skoff + 8] = Wp[1];
            const uint4* Wq = (const uint4*)(Wtl + (size_t)srow * K + k0 + skoff);
            *(uint4*)&Bl[srow * LDSTR + skoff]     = Wq[0];
            *(uint4*)&Bl[srow * LDSTR + skoff + 8] = Wq[1];
        }
        __syncthreads();

        short8 a[4], bh[4], bl[4];
        #pragma unroll
        for (int m = 0; m < 4; ++m)
            a[m] = *(const short8*)&As[(wm * 64 + m * 16 + lr) * LDSTR + lk];
        #pragma unroll
        for (int n = 0; n < 4; ++n) {
            bh[n] = *(const short8*)&Bh[(wn * 64 + n * 16 + lr) * LDSTR + lk];
            bl[n] = *(const short8*)&Bl[(wn * 64 + n * 16 + lr) * LDSTR + lk];
        }
        #pragma unroll
        for (int m = 0; m < 4; ++m)
            #pragma unroll
            for (int n = 0; n < 4; ++n) {
                acc[m][n] = __builtin_amdgcn_mfma_f32_16x16x32_bf16(a[m], bh[n], acc[m][n], 0, 0, 0);
                acc[m][n] = __builtin_amdgcn_mfma_f32_16x16x32_bf16(a[m], bl[n], acc[m][n], 0, 0, 0);
            }
        __syncthreads();
    }

    #pragma unroll
    for (int m = 0; m < 4; ++m) {
        #pragma unroll
        for (int n = 0; n < 4; ++n) {
            int col = wn * 64 + n * 16 + lr;
            #pragma unroll
            for (int j = 0; j < 4; ++j) {
                int row = row0 + wm * 64 + m * 16 + (l >> 4) * 4 + j;
                if (row < nrows)
                    C[(size_t)row * DIM_H + col] = f2bf(acc[m][n][j]);
            }
        }
    }
}

// ---------------------------------------------------------------- aggregation
// 1 wave = 1 node; lanes 0-31 carry item i (uint2 = 4 channels each),
// lanes 32-63 carry item i+1; cross-half __shfl_xor reduce at the end.
__device__ __forceinline__ void agg_acc(const ushort* __restrict__ hin, int s, float w,
                                        int cl, float& a0, float& a1, float& a2, float& a3) {
    uint2 u = ((const uint2*)(hin + (size_t)s * DIM_H))[cl];
    a0 += bf2f((ushort)(u.x & 0xffff)) * w;
    a1 += bf2f((ushort)(u.x >> 16))    * w;
    a2 += bf2f((ushort)(u.y & 0xffff)) * w;
    a3 += bf2f((ushort)(u.y >> 16))    * w;
}

__global__ __launch_bounds__(256) void k_agg(const ushort* __restrict__ hin,
                                             const int* __restrict__ csr,
                                             const int* __restrict__ rp,
                                             const int* __restrict__ bsum,
                                             const int* __restrict__ indeg,
                                             const float* __restrict__ dis,
                                             const float* __restrict__ bias,
                                             ushort* __restrict__ hout) {
    int node = (blockIdx.x * 256 + threadIdx.x) >> 6;
    int lane = threadIdx.x & 63;
    if (node >= N_NODES) return;
    int half = lane >> 5;
    int cl   = lane & 31;
    float di = dis[node];
    int beg = rp[node] + bsum[node >> 8];
    int cnt = indeg[node];

    float a0 = 0.f, a1 = 0.f, a2 = 0.f, a3 = 0.f;

    // first pair: self (low half), edge 0 (high half)
    {
        int s; float w;
        if (half == 0)      { s = node;     w = di * di; }
        else if (cnt >= 1)  { s = csr[beg]; w = dis[s] * di; }
        else                { s = node;     w = 0.f; }
        agg_acc(hin, s, w, cl, a0, a1, a2, a3);
    }
    int m = cnt - 1;                 // remaining edges
    const int* cp = csr + beg + 1;
    int i = 0;
    for (; i + 8 <= m; i += 8) {
        int s0 = cp[i + half],     s1 = cp[i + 2 + half];
        int s2 = cp[i + 4 + half], s3 = cp[i + 6 + half];
        float w0 = dis[s0] * di, w1 = dis[s1] * di;
        float w2 = dis[s2] * di, w3 = dis[s3] * di;
        agg_acc(hin, s0, w0, cl, a0, a1, a2, a3);
        agg_acc(hin, s1, w1, cl, a0, a1, a2, a3);
        agg_acc(hin, s2, w2, cl, a0, a1, a2, a3);
        agg_acc(hin, s3, w3, cl, a0, a1, a2, a3);
    }
    for (; i < m; i += 2) {
        int idx = i + half;
        int s; float w;
        if (idx < m) { s = cp[idx]; w = dis[s] * di; }
        else         { s = node;    w = 0.f; }
        agg_acc(hin, s, w, cl, a0, a1, a2, a3);
    }

    a0 += __shfl_xor(a0, 32);
    a1 += __shfl_xor(a1, 32);
    a2 += __shfl_xor(a2, 32);
    a3 += __shfl_xor(a3, 32);

    if (half == 0) {
        float4 b = ((const float4*)bias)[cl];
        float o0 = fmaxf(a0 + b.x, 0.f), o1 = fmaxf(a1 + b.y, 0.f);
        float o2 = fmaxf(a2 + b.z, 0.f), o3 = fmaxf(a3 + b.w, 0.f);
        uint2 o;
        o.x = (uint)f2bf(o0) | ((uint)f2bf(o1) << 16);
        o.y = (uint)f2bf(o2) | ((uint)f2bf(o3) << 16);
        ((uint2*)(hout + (size_t)node * DIM_H))[cl] = o;
    }
}

// ---------------------------------------------------------------- mean pool (gstart-parallel)
#define PSPLIT 8
__global__ __launch_bounds__(256) void k_pool(const ushort* __restrict__ h,
                                              const int* __restrict__ gstart,
                                              float* __restrict__ pooled) {
    int g  = blockIdx.x >> 3;
    int sp = blockIdx.x & 7;
    int r0 = gstart[g], r1 = gstart[g + 1];
    int count = r1 - r0;
    if (count <= 0) return;
    int chunk = (count + PSPLIT - 1) / PSPLIT;
    int a = r0 + sp * chunk;
    int b = min(a + chunk, r1);
    if (a >= b) return;
    int c  = threadIdx.x & 63;       // channel pair (2 ch)
    int rr = threadIdx.x >> 6;       // row offset 0..3
    float s0 = 0.f, s1 = 0.f;
    for (int r = a + rr; r < b; r += 4) {
        uint u = ((const uint*)(h + (size_t)r * DIM_H))[c];
        s0 += bf2f((ushort)(u & 0xffff));
        s1 += bf2f((ushort)(u >> 16));
    }
    atomicAdd(&pooled[g * DIM_H + 2 * c],     s0);
    atomicAdd(&pooled[g * DIM_H + 2 * c + 1], s1);
}

// ---------------------------------------------------------------- head
__global__ __launch_bounds__(128) void k_head(const float* __restrict__ pooled,
                                              const int* __restrict__ gstart,
                                              const float* __restrict__ Wh,
                                              const float* __restrict__ bh,
                                              float* __restrict__ out) {
    int g = blockIdx.x;
    int c = threadIdx.x;
    float cntg = (float)(gstart[g + 1] - gstart[g]);
    float e = pooled[g * DIM_H + c] / fmaxf(cntg, 1.0f);
    __shared__ float s0[128], s1[128];
    s0[c] = e * Wh[c * 2 + 0];
    s1[c] = e * Wh[c * 2 + 1];
    __syncthreads();
    for (int off = 64; off > 0; off >>= 1) {
        if (c < off) { s0[c] += s0[c + off]; s1[c] += s1[c + off]; }
        __syncthreads();
    }
    if (c == 0) {
        out[g * 2 + 0] = s0[0] + bh[0];
        out[g * 2 + 1] = s1[0] + bh[1];
    }
}

// ---------------------------------------------------------------- launch
extern "C" void kernel_launch(void* const* d_in, const int* in_sizes, int n_in,
                              void* d_out, int out_size, void* d_ws, size_t ws_size,
                              hipStream_t stream) {
    const float* x    = (const float*)d_in[0];
    const int*   esrc = (const int*)d_in[1];
    const int*   edst = esrc + N_EDGES;
    const int*   batch= (const int*)d_in[2];
    const float* W1   = (const float*)d_in[3];
    const float* b1   = (const float*)d_in[4];
    const float* W2   = (const float*)d_in[5];
    const float* b2   = (const float*)d_in[6];
    const float* Wh   = (const float*)d_in[7];
    const float* bh   = (const float*)d_in[8];
    float* out = (float*)d_out;

    char* ws = (char*)d_ws;
    size_t off = 0;
    auto alloc = [&](size_t bytes) {
        void* p = ws + off;
        off += (bytes + 255) & ~(size_t)255;
        return p;
    };
    ushort* bufZ  = (ushort*)alloc((size_t)N_NODES * DIM_H * 2);
    ushort* bufH  = (ushort*)alloc((size_t)N_NODES * DIM_H * 2);
    float*  dis   = (float*)alloc((size_t)N_NODES * 4);
    int*    indeg = (int*)  alloc((size_t)N_NODES * 4);
    int*    rp    = (int*)  alloc((size_t)N_NODES * 4);
    int*    cursor= (int*)  alloc((size_t)N_NODES * 4);
    int*    csr   = (int*)  alloc((size_t)N_EDGES * 4);
    int*    bsum  = (int*)  alloc(512 * 4);
    float*  pooled= (float*)alloc((size_t)N_GRAPHS * DIM_H * 4);
    int*    gstart= (int*)  alloc((N_GRAPHS + 1) * 4);
    ushort* W1th  = (ushort*)alloc((size_t)DIM_IN * DIM_H * 2);
    ushort* W1tl  = (ushort*)alloc((size_t)DIM_IN * DIM_H * 2);
    ushort* W2th  = (ushort*)alloc((size_t)DIM_H * DIM_H * 2);
    ushort* W2tl  = (ushort*)alloc((size_t)DIM_H * DIM_H * 2);

    hipMemsetAsync(indeg,  0, (size_t)N_NODES * 4, stream);
    hipMemsetAsync(cursor, 0, (size_t)N_NODES * 4, stream);
    hipMemsetAsync(pooled, 0, (size_t)N_GRAPHS * DIM_H * 4, stream);

    k_convW  <<<(DIM_IN * DIM_H + 255) / 256, 256, 0, stream>>>(W1, W1th, W1tl, DIM_IN);
    k_convW  <<<(DIM_H * DIM_H + 255) / 256, 256, 0, stream>>>(W2, W2th, W2tl, DIM_H);

    k_indeg  <<<(N_EDGES + 255) / 256, 256, 0, stream>>>(edst, indeg);
    k_scan1  <<<NB_SCAN, 256, 0, stream>>>(indeg, rp, bsum, dis);
    k_scan2  <<<1, 512, 0, stream>>>(bsum);
    k_scatter<<<(N_EDGES + 255) / 256, 256, 0, stream>>>(esrc, edst, rp, bsum, cursor, csr);
    k_gstart <<<1, 128, 0, stream>>>(batch, gstart);

    int gblocks = (N_NODES + 127) / 128;
    k_gemm_mfma<DIM_IN, true ><<<gblocks, 256, 0, stream>>>(x,    W1th, W1tl, bufZ, N_NODES);
    k_agg<<<(N_NODES + 3) / 4, 256, 0, stream>>>(bufZ, csr, rp, bsum, indeg, dis, b1, bufH);
    k_gemm_mfma<DIM_H,  false><<<gblocks, 256, 0, stream>>>(bufH, W2th, W2tl, bufZ, N_NODES);
    k_agg<<<(N_NODES + 3) / 4, 256, 0, stream>>>(bufZ, csr, rp, bsum, indeg, dis, b2, bufH);

    k_pool<<<N_GRAPHS * PSPLIT, 256, 0, stream>>>(bufH, gstart, pooled);
    k_head<<<N_GRAPHS, 128, 0, stream>>>(pooled, gstart, Wh, bh, out);
}

// Round 4
// 453.380 us; speedup vs baseline: 1.9672x; 1.0765x over previous
//
#include <hip/hip_runtime.h>
#include <hip/hip_bf16.h>

static constexpr int N_NODES  = 100000;
static constexpr int N_EDGES  = 1600000;
static constexpr int DIM_IN   = 768;
static constexpr int DIM_H    = 128;
static constexpr int N_GRAPHS = 64;
static constexpr int NB_SCAN  = (N_NODES + 255) / 256;   // 391

typedef __attribute__((ext_vector_type(8))) short short8;
typedef __attribute__((ext_vector_type(4))) float f32x4;

__device__ __forceinline__ ushort f2bf(float f) {   // RNE, finite inputs
    union { float f; uint u; } v; v.f = f;
    uint r = v.u + 0x7fffu + ((v.u >> 16) & 1u);
    return (ushort)(r >> 16);
}
__device__ __forceinline__ float bf2f(ushort u) {
    union { uint u; float f; } v; v.u = ((uint)u) << 16;
    return v.f;
}

// ---------------------------------------------------------------- degree
__global__ void k_indeg(const int* __restrict__ edst, int* __restrict__ indeg) {
    int e = blockIdx.x * 256 + threadIdx.x;
    if (e < N_EDGES) atomicAdd(&indeg[edst[e]], 1);
}

// ---------------------------------------------------------------- scan (+dis fold)
__global__ void k_scan1(const int* __restrict__ indeg, int* __restrict__ rp,
                        int* __restrict__ bsum, float* __restrict__ dis) {
    __shared__ int s[256];
    int t = threadIdx.x;
    int i = blockIdx.x * 256 + t;
    int v = (i < N_NODES) ? indeg[i] : 0;
    s[t] = v;
    __syncthreads();
    for (int off = 1; off < 256; off <<= 1) {
        int x = (t >= off) ? s[t - off] : 0;
        __syncthreads();
        s[t] += x;
        __syncthreads();
    }
    if (i < N_NODES) {
        rp[i] = s[t] - v;                       // exclusive (block-local)
        dis[i] = rsqrtf((float)v + 1.0f);       // +1 = self loop
    }
    if (t == 255) bsum[blockIdx.x] = s[255];
}

// scan of block sums + gstart binary searches on idle threads
__global__ void k_scan2(int* __restrict__ bsum, const int* __restrict__ batch,
                        int* __restrict__ gstart) {
    __shared__ int s[512];
    int t = threadIdx.x;
    int v = (t < NB_SCAN) ? bsum[t] : 0;
    s[t] = v;
    __syncthreads();
    for (int off = 1; off < 512; off <<= 1) {
        int x = (t >= off) ? s[t - off] : 0;
        __syncthreads();
        s[t] += x;
        __syncthreads();
    }
    if (t < NB_SCAN) bsum[t] = s[t] - v;        // exclusive block offsets
    if (t <= N_GRAPHS) {                        // lower_bound(batch, t)
        int lo = 0, hi = N_NODES;
        while (lo < hi) {
            int mid = (lo + hi) >> 1;
            if (batch[mid] < t) lo = mid + 1; else hi = mid;
        }
        gstart[t] = lo;
    }
}

// ---------------------------------------------------------------- CSR scatter: (src, dis[src]) pairs
__global__ void k_scatter(const int* __restrict__ esrc, const int* __restrict__ edst,
                          const int* __restrict__ rp, const int* __restrict__ bsum,
                          const float* __restrict__ dis,
                          int* __restrict__ cursor, uint2* __restrict__ csrw) {
    int e = blockIdx.x * 256 + threadIdx.x;
    if (e >= N_EDGES) return;
    int d = edst[e];
    int sv = esrc[e];
    int pos = atomicAdd(&cursor[d], 1);
    uint2 val;
    val.x = (uint)sv;
    val.y = __float_as_uint(dis[sv]);
    csrw[rp[d] + bsum[d >> 8] + pos] = val;
}

// ---------------------------------------------------------------- W convert (both layers, one launch)
__global__ void k_convW(const float* __restrict__ W1, const float* __restrict__ W2,
                        ushort* __restrict__ W1th, ushort* __restrict__ W1tl,
                        ushort* __restrict__ W2th, ushort* __restrict__ W2tl) {
    int i = blockIdx.x * 256 + threadIdx.x;
    const int total1 = DIM_IN * DIM_H;
    if (i < total1) {
        int k = i >> 7, n = i & 127;
        float w = W1[i];
        ushort h = f2bf(w);
        ushort lo = f2bf(w - bf2f(h));
        W1th[(size_t)n * DIM_IN + k] = h;
        W1tl[(size_t)n * DIM_IN + k] = lo;
    } else {
        int j = i - total1;
        if (j < DIM_H * DIM_H) {
            int k = j >> 7, n = j & 127;
            float w = W2[j];
            ushort h = f2bf(w);
            ushort lo = f2bf(w - bf2f(h));
            W2th[(size_t)n * DIM_H + k] = h;
            W2tl[(size_t)n * DIM_H + k] = lo;
        }
    }
}

// ---------------------------------------------------------------- MFMA GEMM
// C[nrows][128](bf16) = A[nrows][K] @ (W_hi + W_lo)   (W stored transposed [128][K])
#define LDSTR 40

template<int K, bool AFP32>
__global__ __launch_bounds__(256) void k_gemm_mfma(const void* __restrict__ Av,
                                                   const ushort* __restrict__ Wth,
                                                   const ushort* __restrict__ Wtl,
                                                   ushort* __restrict__ C,
                                                   int nrows) {
    __shared__ ushort As[128 * LDSTR];
    __shared__ ushort Bh[128 * LDSTR];
    __shared__ ushort Bl[128 * LDSTR];

    const int t = threadIdx.x;
    const int row0 = blockIdx.x * 128;
    const int srow = t >> 1;
    const int skoff = (t & 1) * 16;
    const int l = t & 63;
    const int wv = t >> 6;
    const int wm = wv >> 1, wn = wv & 1;
    const int lr = l & 15;
    const int lk = (l >> 4) * 8;

    f32x4 acc[4][4];
    const f32x4 zero = {0.f, 0.f, 0.f, 0.f};
    #pragma unroll
    for (int m = 0; m < 4; ++m)
        #pragma unroll
        for (int n = 0; n < 4; ++n) acc[m][n] = zero;

    for (int k0 = 0; k0 < K; k0 += 32) {
        {
            uint p[8];
            if (AFP32) {
                float f[16];
                if (row0 + srow < nrows) {
                    const float4* Ap = (const float4*)((const float*)Av +
                        (size_t)(row0 + srow) * K + k0 + skoff);
                    *(float4*)&f[0]  = Ap[0];
                    *(float4*)&f[4]  = Ap[1];
                    *(float4*)&f[8]  = Ap[2];
                    *(float4*)&f[12] = Ap[3];
                } else {
                    #pragma unroll
                    for (int i = 0; i < 16; ++i) f[i] = 0.f;
                }
                #pragma unroll
                for (int i = 0; i < 8; ++i)
                    p[i] = (uint)f2bf(f[2 * i]) | ((uint)f2bf(f[2 * i + 1]) << 16);
            } else {
                uint4 q0 = {0, 0, 0, 0}, q1 = {0, 0, 0, 0};
                if (row0 + srow < nrows) {
                    const uint4* Ap = (const uint4*)((const ushort*)Av +
                        (size_t)(row0 + srow) * K + k0 + skoff);
                    q0 = Ap[0]; q1 = Ap[1];
                }
                p[0] = q0.x; p[1] = q0.y; p[2] = q0.z; p[3] = q0.w;
                p[4] = q1.x; p[5] = q1.y; p[6] = q1.z; p[7] = q1.w;
            }
            uint4 w0 = {p[0], p[1], p[2], p[3]};
            uint4 w1 = {p[4], p[5], p[6], p[7]};
            *(uint4*)&As[srow * LDSTR + skoff]     = w0;
            *(uint4*)&As[srow * LDSTR + skoff + 8] = w1;
        }
        {
            const uint4* Wp = (const uint4*)(Wth + (size_t)srow * K + k0 + skoff);
            *(uint4*)&Bh[srow * LDSTR + skoff]     = Wp[0];
            *(uint4*)&Bh[srow * LDSTR + skoff + 8] = Wp[1];
            const uint4* Wq = (const uint4*)(Wtl + (size_t)srow * K + k0 + skoff);
            *(uint4*)&Bl[srow * LDSTR + skoff]     = Wq[0];
            *(uint4*)&Bl[srow * LDSTR + skoff + 8] = Wq[1];
        }
        __syncthreads();

        short8 a[4], bh[4], bl[4];
        #pragma unroll
        for (int m = 0; m < 4; ++m)
            a[m] = *(const short8*)&As[(wm * 64 + m * 16 + lr) * LDSTR + lk];
        #pragma unroll
        for (int n = 0; n < 4; ++n) {
            bh[n] = *(const short8*)&Bh[(wn * 64 + n * 16 + lr) * LDSTR + lk];
            bl[n] = *(const short8*)&Bl[(wn * 64 + n * 16 + lr) * LDSTR + lk];
        }
        #pragma unroll
        for (int m = 0; m < 4; ++m)
            #pragma unroll
            for (int n = 0; n < 4; ++n) {
                acc[m][n] = __builtin_amdgcn_mfma_f32_16x16x32_bf16(a[m], bh[n], acc[m][n], 0, 0, 0);
                acc[m][n] = __builtin_amdgcn_mfma_f32_16x16x32_bf16(a[m], bl[n], acc[m][n], 0, 0, 0);
            }
        __syncthreads();
    }

    #pragma unroll
    for (int m = 0; m < 4; ++m) {
        #pragma unroll
        for (int n = 0; n < 4; ++n) {
            int col = wn * 64 + n * 16 + lr;
            #pragma unroll
            for (int j = 0; j < 4; ++j) {
                int row = row0 + wm * 64 + m * 16 + (l >> 4) * 4 + j;
                if (row < nrows)
                    C[(size_t)row * DIM_H + col] = f2bf(acc[m][n][j]);
            }
        }
    }
}

// ---------------------------------------------------------------- aggregation
// 1 wave = 1 node; quarter-wave (16 lanes) x uint4 = one 256B row per quarter,
// 4 edges in flight per load instruction; 2x shfl_xor cross-quarter reduce.
__device__ __forceinline__ void acc8(uint4 u, float w, float* a) {
    a[0] += bf2f((ushort)(u.x & 0xffff)) * w;
    a[1] += bf2f((ushort)(u.x >> 16))    * w;
    a[2] += bf2f((ushort)(u.y & 0xffff)) * w;
    a[3] += bf2f((ushort)(u.y >> 16))    * w;
    a[4] += bf2f((ushort)(u.z & 0xffff)) * w;
    a[5] += bf2f((ushort)(u.z >> 16))    * w;
    a[6] += bf2f((ushort)(u.w & 0xffff)) * w;
    a[7] += bf2f((ushort)(u.w >> 16))    * w;
}

__global__ __launch_bounds__(256) void k_agg(const ushort* __restrict__ hin,
                                             const uint2* __restrict__ csrw,
                                             const int* __restrict__ rp,
                                             const int* __restrict__ bsum,
                                             const int* __restrict__ indeg,
                                             const float* __restrict__ dis,
                                             const float* __restrict__ bias,
                                             ushort* __restrict__ hout) {
    int node = (blockIdx.x * 256 + threadIdx.x) >> 6;
    int lane = threadIdx.x & 63;
    if (node >= N_NODES) return;
    int q  = lane >> 4;          // quarter 0..3
    int cl = lane & 15;          // 8-channel group within row
    float di = dis[node];
    int beg = rp[node] + bsum[node >> 8];
    int cnt = indeg[node];

    float a[8] = {0.f, 0.f, 0.f, 0.f, 0.f, 0.f, 0.f, 0.f};

    // prologue group: {self, e0, e1, e2}
    {
        uint s; float w;
        if (q == 0)             { s = (uint)node; w = di * di; }
        else if (q - 1 < cnt)   { uint2 p = csrw[beg + q - 1]; s = p.x; w = __uint_as_float(p.y) * di; }
        else                    { s = (uint)node; w = 0.f; }
        uint4 u = ((const uint4*)(hin + (size_t)s * DIM_H))[cl];
        acc8(u, w, a);
    }
    const uint2* cp = csrw + beg + 3;
    int m = cnt - 3;
    int i = 0;
    for (; i + 8 <= m; i += 8) {
        uint2 p0 = cp[i + q];
        uint2 p1 = cp[i + 4 + q];
        float w0 = __uint_as_float(p0.y) * di;
        float w1 = __uint_as_float(p1.y) * di;
        uint4 u0 = ((const uint4*)(hin + (size_t)p0.x * DIM_H))[cl];
        uint4 u1 = ((const uint4*)(hin + (size_t)p1.x * DIM_H))[cl];
        acc8(u0, w0, a);
        acc8(u1, w1, a);
    }
    for (; i < m; i += 4) {
        int idx = i + q;
        uint s; float w;
        if (idx < m) { uint2 p = cp[idx]; s = p.x; w = __uint_as_float(p.y) * di; }
        else         { s = (uint)node;    w = 0.f; }
        uint4 u = ((const uint4*)(hin + (size_t)s * DIM_H))[cl];
        acc8(u, w, a);
    }

    #pragma unroll
    for (int j = 0; j < 8; ++j) {
        a[j] += __shfl_xor(a[j], 16);
        a[j] += __shfl_xor(a[j], 32);
    }

    if (q == 0) {
        float4 b0 = ((const float4*)bias)[cl * 2];
        float4 b1 = ((const float4*)bias)[cl * 2 + 1];
        float o0 = fmaxf(a[0] + b0.x, 0.f), o1 = fmaxf(a[1] + b0.y, 0.f);
        float o2 = fmaxf(a[2] + b0.z, 0.f), o3 = fmaxf(a[3] + b0.w, 0.f);
        float o4 = fmaxf(a[4] + b1.x, 0.f), o5 = fmaxf(a[5] + b1.y, 0.f);
        float o6 = fmaxf(a[6] + b1.z, 0.f), o7 = fmaxf(a[7] + b1.w, 0.f);
        uint4 o;
        o.x = (uint)f2bf(o0) | ((uint)f2bf(o1) << 16);
        o.y = (uint)f2bf(o2) | ((uint)f2bf(o3) << 16);
        o.z = (uint)f2bf(o4) | ((uint)f2bf(o5) << 16);
        o.w = (uint)f2bf(o6) | ((uint)f2bf(o7) << 16);
        ((uint4*)(hout + (size_t)node * DIM_H))[cl] = o;
    }
}

// ---------------------------------------------------------------- mean pool: per-split partials, no atomics
#define PSPLIT 8
__global__ __launch_bounds__(256) void k_pool(const ushort* __restrict__ h,
                                              const int* __restrict__ gstart,
                                              float* __restrict__ pooled2) {
    int g  = blockIdx.x >> 3;
    int sp = blockIdx.x & 7;
    int r0 = gstart[g], r1 = gstart[g + 1];
    int count = r1 - r0;
    int chunk = (count + PSPLIT - 1) / PSPLIT;
    int aS = r0 + sp * chunk;
    int bE = min(aS + chunk, r1);
    int c  = threadIdx.x & 63;       // uint channel pair
    int rr = threadIdx.x >> 6;       // row offset 0..3
    float s0 = 0.f, s1 = 0.f;
    for (int r = aS + rr; r < bE; r += 4) {
        uint u = ((const uint*)(h + (size_t)r * DIM_H))[c];
        s0 += bf2f((ushort)(u & 0xffff));
        s1 += bf2f((ushort)(u >> 16));
    }
    __shared__ float sm0[4][64], sm1[4][64];
    sm0[rr][c] = s0; sm1[rr][c] = s1;
    __syncthreads();
    if (rr == 0) {
        float v0 = sm0[0][c] + sm0[1][c] + sm0[2][c] + sm0[3][c];
        float v1 = sm1[0][c] + sm1[1][c] + sm1[2][c] + sm1[3][c];
        float* dst = pooled2 + (size_t)(g * PSPLIT + sp) * DIM_H;
        dst[2 * c]     = v0;
        dst[2 * c + 1] = v1;
    }
}

// ---------------------------------------------------------------- head (sums 8 partials)
__global__ __launch_bounds__(128) void k_head(const float* __restrict__ pooled2,
                                              const int* __restrict__ gstart,
                                              const float* __restrict__ Wh,
                                              const float* __restrict__ bh,
                                              float* __restrict__ out) {
    int g = blockIdx.x;
    int c = threadIdx.x;
    float s = 0.f;
    #pragma unroll
    for (int sp = 0; sp < PSPLIT; ++sp)
        s += pooled2[(size_t)(g * PSPLIT + sp) * DIM_H + c];
    float cntg = (float)(gstart[g + 1] - gstart[g]);
    float e = s / fmaxf(cntg, 1.0f);
    __shared__ float s0[128], s1[128];
    s0[c] = e * Wh[c * 2 + 0];
    s1[c] = e * Wh[c * 2 + 1];
    __syncthreads();
    for (int off = 64; off > 0; off >>= 1) {
        if (c < off) { s0[c] += s0[c + off]; s1[c] += s1[c + off]; }
        __syncthreads();
    }
    if (c == 0) {
        out[g * 2 + 0] = s0[0] + bh[0];
        out[g * 2 + 1] = s1[0] + bh[1];
    }
}

// ---------------------------------------------------------------- launch
extern "C" void kernel_launch(void* const* d_in, const int* in_sizes, int n_in,
                              void* d_out, int out_size, void* d_ws, size_t ws_size,
                              hipStream_t stream) {
    const float* x    = (const float*)d_in[0];
    const int*   esrc = (const int*)d_in[1];
    const int*   edst = esrc + N_EDGES;
    const int*   batch= (const int*)d_in[2];
    const float* W1   = (const float*)d_in[3];
    const float* b1   = (const float*)d_in[4];
    const float* W2   = (const float*)d_in[5];
    const float* b2   = (const float*)d_in[6];
    const float* Wh   = (const float*)d_in[7];
    const float* bh   = (const float*)d_in[8];
    float* out = (float*)d_out;

    char* ws = (char*)d_ws;
    size_t off = 0;
    auto alloc = [&](size_t bytes) {
        void* p = ws + off;
        off += (bytes + 255) & ~(size_t)255;
        return p;
    };
    ushort* bufZ   = (ushort*)alloc((size_t)N_NODES * DIM_H * 2);
    ushort* bufH   = (ushort*)alloc((size_t)N_NODES * DIM_H * 2);
    float*  dis    = (float*)alloc((size_t)N_NODES * 4);
    int*    deg2   = (int*)  alloc((size_t)2 * N_NODES * 4);   // indeg | cursor
    int*    indeg  = deg2;
    int*    cursor = deg2 + N_NODES;
    int*    rp     = (int*)  alloc((size_t)N_NODES * 4);
    uint2*  csrw   = (uint2*)alloc((size_t)N_EDGES * 8);
    int*    bsum   = (int*)  alloc(512 * 4);
    float*  pooled2= (float*)alloc((size_t)N_GRAPHS * PSPLIT * DIM_H * 4);
    int*    gstart = (int*)  alloc((N_GRAPHS + 1) * 4);
    ushort* W1th   = (ushort*)alloc((size_t)DIM_IN * DIM_H * 2);
    ushort* W1tl   = (ushort*)alloc((size_t)DIM_IN * DIM_H * 2);
    ushort* W2th   = (ushort*)alloc((size_t)DIM_H * DIM_H * 2);
    ushort* W2tl   = (ushort*)alloc((size_t)DIM_H * DIM_H * 2);

    hipMemsetAsync(deg2, 0, (size_t)2 * N_NODES * 4, stream);

    int convblocks = (DIM_IN * DIM_H + DIM_H * DIM_H + 255) / 256;
    k_convW  <<<convblocks, 256, 0, stream>>>(W1, W2, W1th, W1tl, W2th, W2tl);

    k_indeg  <<<(N_EDGES + 255) / 256, 256, 0, stream>>>(edst, indeg);
    k_scan1  <<<NB_SCAN, 256, 0, stream>>>(indeg, rp, bsum, dis);
    k_scan2  <<<1, 512, 0, stream>>>(bsum, batch, gstart);
    k_scatter<<<(N_EDGES + 255) / 256, 256, 0, stream>>>(esrc, edst, rp, bsum, dis, cursor, csrw);

    int gblocks = (N_NODES + 127) / 128;
    k_gemm_mfma<DIM_IN, true ><<<gblocks, 256, 0, stream>>>(x,    W1th, W1tl, bufZ, N_NODES);
    k_agg<<<(N_NODES + 3) / 4, 256, 0, stream>>>(bufZ, csrw, rp, bsum, indeg, dis, b1, bufH);
    k_gemm_mfma<DIM_H,  false><<<gblocks, 256, 0, stream>>>(bufH, W2th, W2tl, bufZ, N_NODES);
    k_agg<<<(N_NODES + 3) / 4, 256, 0, stream>>>(bufZ, csrw, rp, bsum, indeg, dis, b2, bufH);

    k_pool<<<N_GRAPHS * PSPLIT, 256, 0, stream>>>(bufH, gstart, pooled2);
    k_head<<<N_GRAPHS, 128, 0, stream>>>(pooled2, gstart, Wh, bh, out);
}